// Round 1
// baseline (80.011 us; speedup 1.0000x reference)
//
#include <hip/hip_runtime.h>

#define IMG_W 224
#define IMG_H 224
#define IMG_N (IMG_W * IMG_H)   // 50176
#define NBATCH 2048
#define BLK 256

__global__ __launch_bounds__(BLK) void attn_overlap_per_image(
    const float* __restrict__ attn,
    const int* __restrict__ bboxes,
    float* __restrict__ partial)
{
    const int b = blockIdx.x;
    const float4* __restrict__ img4 =
        reinterpret_cast<const float4*>(attn + (size_t)b * IMG_N);

    // clamped inclusive box
    int X1 = bboxes[4 * b + 0];
    int Y1 = bboxes[4 * b + 1];
    int X2 = bboxes[4 * b + 2];
    int Y2 = bboxes[4 * b + 3];
    X1 = min(max(X1, 0), IMG_W - 1);
    Y1 = min(max(Y1, 0), IMG_H - 1);
    X2 = min(max(X2, 0), IMG_W - 1);
    Y2 = min(max(Y2, 0), IMG_H - 1);

    float lmin = 3.402823466e38f;
    float lmax = -3.402823466e38f;
    float lsum = 0.0f;
    float lin  = 0.0f;

    const int N4 = IMG_N / 4;  // 12544; W=224 divisible by 4 -> each float4 is one row
    for (int i = threadIdx.x; i < N4; i += BLK) {
        float4 v = img4[i];
        int base = i * 4;
        int row = base / IMG_W;      // strength-reduced by compiler (magic mul)
        int col = base - row * IMG_W;

        lmin = fminf(lmin, fminf(fminf(v.x, v.y), fminf(v.z, v.w)));
        lmax = fmaxf(lmax, fmaxf(fmaxf(v.x, v.y), fmaxf(v.z, v.w)));
        lsum += (v.x + v.y) + (v.z + v.w);

        if (row >= Y1 && row <= Y2) {
            float s = 0.0f;
            if (col     >= X1 && col     <= X2) s += v.x;
            if (col + 1 >= X1 && col + 1 <= X2) s += v.y;
            if (col + 2 >= X1 && col + 2 <= X2) s += v.z;
            if (col + 3 >= X1 && col + 3 <= X2) s += v.w;
            lin += s;
        }
    }

    // 64-lane wave butterfly reduce
    #pragma unroll
    for (int off = 32; off >= 1; off >>= 1) {
        lmin = fminf(lmin, __shfl_xor(lmin, off));
        lmax = fmaxf(lmax, __shfl_xor(lmax, off));
        lsum += __shfl_xor(lsum, off);
        lin  += __shfl_xor(lin,  off);
    }

    __shared__ float smin[4], smax[4], ssum[4], sins[4];
    const int wave = threadIdx.x >> 6;
    const int lane = threadIdx.x & 63;
    if (lane == 0) { smin[wave] = lmin; smax[wave] = lmax; ssum[wave] = lsum; sins[wave] = lin; }
    __syncthreads();

    if (threadIdx.x == 0) {
        const float eps = 1e-8f;
        float mn  = fminf(fminf(smin[0], smin[1]), fminf(smin[2], smin[3]));
        float mx  = fmaxf(fmaxf(smax[0], smax[1]), fmaxf(smax[2], smax[3]));
        float Sx  = (ssum[0] + ssum[1]) + (ssum[2] + ssum[3]);
        float Sin = (sins[0] + sins[1]) + (sins[2] + sins[3]);

        float d = mx - mn + eps;
        int rows_in = (Y2 >= Y1) ? (Y2 - Y1 + 1) : 0;
        int cols_in = (X2 >= X1) ? (X2 - X1 + 1) : 0;
        float cnt = (float)(rows_in * cols_in);

        float S       = (Sx  - (float)IMG_N * mn) / d;   // sum of minmax-normalized map
        float Sinside = (Sin - cnt * mn) / d;            // its in-box portion
        partial[b] = (S - Sinside) / (S + eps);
    }
}

__global__ __launch_bounds__(BLK) void attn_overlap_mean(
    const float* __restrict__ partial, float* __restrict__ out)
{
    float s = 0.0f;
    for (int i = threadIdx.x; i < NBATCH; i += BLK) s += partial[i];
    #pragma unroll
    for (int off = 32; off >= 1; off >>= 1) s += __shfl_xor(s, off);

    __shared__ float ss[4];
    const int wave = threadIdx.x >> 6;
    const int lane = threadIdx.x & 63;
    if (lane == 0) ss[wave] = s;
    __syncthreads();
    if (threadIdx.x == 0)
        out[0] = ((ss[0] + ss[1]) + (ss[2] + ss[3])) / (float)NBATCH;
}

extern "C" void kernel_launch(void* const* d_in, const int* in_sizes, int n_in,
                              void* d_out, int out_size, void* d_ws, size_t ws_size,
                              hipStream_t stream) {
    const float* attn   = (const float*)d_in[0];
    const int*   bboxes = (const int*)d_in[1];   // int64 in ref -> int32 on device (jax x64 off)
    float* out = (float*)d_out;
    float* partial = (float*)d_ws;               // 2048 floats

    attn_overlap_per_image<<<NBATCH, BLK, 0, stream>>>(attn, bboxes, partial);
    attn_overlap_mean<<<1, BLK, 0, stream>>>(partial, out);
}

// Round 3
// 65.642 us; speedup vs baseline: 1.2189x; 1.2189x over previous
//
#include <hip/hip_runtime.h>

#define IMG_W 224
#define IMG_H 224
#define IMG_N (IMG_W * IMG_H)   // 50176
#define NBATCH 2048
#define BLK 256
#define N4 (IMG_N / 4)          // 12544 float4 per image
#define ITERS (N4 / BLK)        // 49, exact

typedef float f32x4 __attribute__((ext_vector_type(4)));

__global__ __launch_bounds__(BLK) void attn_overlap_per_image(
    const float* __restrict__ attn,
    const int* __restrict__ bboxes,
    float* __restrict__ partial)
{
    const int b = blockIdx.x;
    const f32x4* __restrict__ img4 =
        reinterpret_cast<const f32x4*>(attn + (size_t)b * IMG_N);

    // clamped inclusive box (block-uniform scalar work)
    const int4 bb = reinterpret_cast<const int4*>(bboxes)[b];
    int X1 = min(max(bb.x, 0), IMG_W - 1);
    int Y1 = min(max(bb.y, 0), IMG_H - 1);
    int X2 = min(max(bb.z, 0), IMG_W - 1);
    int Y2 = min(max(bb.w, 0), IMG_H - 1);
    // normalize empty boxes to an impossible range so the unsigned test is false
    if (X2 < X1) { X1 = IMG_W; X2 = IMG_W; }
    if (Y2 < Y1) { Y1 = IMG_H; Y2 = IMG_H; }
    const unsigned uXD = (unsigned)(X2 - X1);
    const unsigned uYD = (unsigned)(Y2 - Y1);

    float lmin = 3.402823466e38f;
    float lmax = -3.402823466e38f;
    float lsum = 0.0f;
    float lin  = 0.0f;

    // incremental row / col4 tracking: i = tid + j*BLK; 256 = 4*56 + 32
    int row = (int)threadIdx.x / 56;
    int c4  = (int)threadIdx.x % 56;

    #pragma unroll 7
    for (int j = 0; j < ITERS; ++j) {
        const f32x4 v = __builtin_nontemporal_load(&img4[threadIdx.x + j * BLK]);

        lmin = fminf(fminf(fminf(v.x, v.y), fminf(v.z, v.w)), lmin);
        lmax = fmaxf(fmaxf(fmaxf(v.x, v.y), fmaxf(v.z, v.w)), lmax);
        lsum += (v.x + v.y) + (v.z + v.w);

        const unsigned ux = (unsigned)(c4 * 4 - X1);
        float s = 0.0f;
        s += (ux      <= uXD) ? v.x : 0.0f;
        s += (ux + 1u <= uXD) ? v.y : 0.0f;
        s += (ux + 2u <= uXD) ? v.z : 0.0f;
        s += (ux + 3u <= uXD) ? v.w : 0.0f;
        const bool rowin = (unsigned)(row - Y1) <= uYD;
        lin += rowin ? s : 0.0f;

        // advance by 256 float4s: +4 rows, +32 col4, with single carry
        row += 4; c4 += 32;
        if (c4 >= 56) { c4 -= 56; row += 1; }
    }

    // 64-lane wave butterfly reduce
    #pragma unroll
    for (int off = 32; off >= 1; off >>= 1) {
        lmin = fminf(lmin, __shfl_xor(lmin, off));
        lmax = fmaxf(lmax, __shfl_xor(lmax, off));
        lsum += __shfl_xor(lsum, off);
        lin  += __shfl_xor(lin,  off);
    }

    __shared__ float smin[4], smax[4], ssum[4], sins[4];
    const int wave = threadIdx.x >> 6;
    const int lane = threadIdx.x & 63;
    if (lane == 0) { smin[wave] = lmin; smax[wave] = lmax; ssum[wave] = lsum; sins[wave] = lin; }
    __syncthreads();

    if (threadIdx.x == 0) {
        const float eps = 1e-8f;
        float mn  = fminf(fminf(smin[0], smin[1]), fminf(smin[2], smin[3]));
        float mx  = fmaxf(fmaxf(smax[0], smax[1]), fmaxf(smax[2], smax[3]));
        float Sx  = (ssum[0] + ssum[1]) + (ssum[2] + ssum[3]);
        float Sin = (sins[0] + sins[1]) + (sins[2] + sins[3]);

        float d = mx - mn + eps;
        float cnt = (X1 < IMG_W && Y1 < IMG_H)
                  ? (float)((X2 - X1 + 1) * (Y2 - Y1 + 1)) : 0.0f;

        float S       = (Sx  - (float)IMG_N * mn) / d;   // sum of minmax-normalized map
        float Sinside = (Sin - cnt * mn) / d;            // its in-box portion
        partial[b] = (S - Sinside) / (S + eps);
    }
}

__global__ __launch_bounds__(BLK) void attn_overlap_mean(
    const float* __restrict__ partial, float* __restrict__ out)
{
    float s = 0.0f;
    #pragma unroll
    for (int k = 0; k < NBATCH / BLK; ++k) s += partial[threadIdx.x + k * BLK];
    #pragma unroll
    for (int off = 32; off >= 1; off >>= 1) s += __shfl_xor(s, off);

    __shared__ float ss[4];
    const int wave = threadIdx.x >> 6;
    const int lane = threadIdx.x & 63;
    if (lane == 0) ss[wave] = s;
    __syncthreads();
    if (threadIdx.x == 0)
        out[0] = ((ss[0] + ss[1]) + (ss[2] + ss[3])) / (float)NBATCH;
}

extern "C" void kernel_launch(void* const* d_in, const int* in_sizes, int n_in,
                              void* d_out, int out_size, void* d_ws, size_t ws_size,
                              hipStream_t stream) {
    const float* attn   = (const float*)d_in[0];
    const int*   bboxes = (const int*)d_in[1];   // int64 in ref -> int32 on device (jax x64 off)
    float* out = (float*)d_out;
    float* partial = (float*)d_ws;               // 2048 floats

    attn_overlap_per_image<<<NBATCH, BLK, 0, stream>>>(attn, bboxes, partial);
    attn_overlap_mean<<<1, BLK, 0, stream>>>(partial, out);
}